// Round 1
// baseline (300.690 us; speedup 1.0000x reference)
//
#include <hip/hip_runtime.h>

// AdultConnectomeNetwork: 3 layers of  x = A @ (W @ x) + bias
// A and W share the same sorted-COO pattern (rows sorted, cols random).
// N=50000, NNZ=800000, B=64, L=3.
//
// Strategy:
//  - rows is sorted -> build CSR row_ptr via per-row binary search (cheap).
//  - SpMM: 16 lanes per row, each lane owns a float4 (4 of the 64 columns).
//    Gather of x[col, :] is a coalesced 256B read per edge. Accumulate in
//    registers, no atomics.
//  - d_out serves as the x ping-pong buffer; d_ws holds row_ptr + y buffer.

__global__ void build_row_ptr_kernel(const int* __restrict__ rows, int nnz,
                                     int n, int* __restrict__ row_ptr) {
    int r = blockIdx.x * blockDim.x + threadIdx.x;
    if (r > n) return;
    // lower_bound(rows, r)
    int lo = 0, hi = nnz;
    while (lo < hi) {
        int mid = (lo + hi) >> 1;
        if (rows[mid] < r) lo = mid + 1; else hi = mid;
    }
    row_ptr[r] = lo;
}

// y[r, :] = sum_{e in row r} vals[e] * x[cols[e], :]  (+ bias[r] if ADD_BIAS)
// 16 threads per row; lane l owns columns [4l, 4l+4).
template <bool ADD_BIAS>
__global__ void spmm_kernel(const float* __restrict__ vals,
                            const int* __restrict__ cols,
                            const int* __restrict__ row_ptr,
                            const float4* __restrict__ xin,  // [n*16] float4
                            const float* __restrict__ bias,
                            float4* __restrict__ yout,       // [n*16] float4
                            int n) {
    const int groups_per_block = blockDim.x >> 4;           // 16 lanes/row
    const int row = blockIdx.x * groups_per_block + (threadIdx.x >> 4);
    const int lane = threadIdx.x & 15;
    if (row >= n) return;

    const int e0 = row_ptr[row];
    const int e1 = row_ptr[row + 1];

    float4 acc = make_float4(0.f, 0.f, 0.f, 0.f);
    for (int e = e0; e < e1; ++e) {
        const float v = vals[e];
        const int c = cols[e];
        const float4 xv = xin[c * 16 + lane];
        acc.x += v * xv.x;
        acc.y += v * xv.y;
        acc.z += v * xv.z;
        acc.w += v * xv.w;
    }
    if (ADD_BIAS) {
        const float b = bias[row];
        acc.x += b; acc.y += b; acc.z += b; acc.w += b;
    }
    yout[row * 16 + lane] = acc;
}

extern "C" void kernel_launch(void* const* d_in, const int* in_sizes, int n_in,
                              void* d_out, int out_size, void* d_ws, size_t ws_size,
                              hipStream_t stream) {
    const float* x_in     = (const float*)d_in[0];  // (N, 64)
    const float* adj_vals = (const float*)d_in[1];  // (NNZ,)
    const float* w_vals   = (const float*)d_in[2];  // (NNZ,)
    const float* bias     = (const float*)d_in[3];  // (N,)
    const int*   rows     = (const int*)d_in[4];    // (NNZ,) sorted
    const int*   cols     = (const int*)d_in[5];    // (NNZ,)
    // d_in[6] = n_layers (device scalar); structurally 3 in this problem.

    const int N   = in_sizes[3];
    const int NNZ = in_sizes[1];

    // Workspace layout: row_ptr (N+1 ints, 256B-aligned), then y buffer (N*64 f32)
    int* row_ptr = (int*)d_ws;
    size_t rp_bytes = ((size_t)(N + 1) * sizeof(int) + 255) & ~(size_t)255;
    float* ybuf = (float*)((char*)d_ws + rp_bytes);

    float* xbuf = (float*)d_out;   // ping-pong x lives in d_out

    // 1) CSR row pointers
    {
        int threads = 256;
        int blocks = (N + 1 + threads - 1) / threads;
        build_row_ptr_kernel<<<blocks, threads, 0, stream>>>(rows, NNZ, N, row_ptr);
    }

    // 2) Three layers: y = W@x ; x = A@y + bias
    const int threads = 256;
    const int rows_per_block = threads / 16;
    const int blocks = (N + rows_per_block - 1) / rows_per_block;

    const float4* x4_in = (const float4*)x_in;
    float4* y4 = (float4*)ybuf;
    float4* x4 = (float4*)xbuf;

    // layer 1
    spmm_kernel<false><<<blocks, threads, 0, stream>>>(w_vals, cols, row_ptr,
                                                       x4_in, nullptr, y4, N);
    spmm_kernel<true><<<blocks, threads, 0, stream>>>(adj_vals, cols, row_ptr,
                                                      (const float4*)y4, bias, x4, N);
    // layer 2
    spmm_kernel<false><<<blocks, threads, 0, stream>>>(w_vals, cols, row_ptr,
                                                       (const float4*)x4, nullptr, y4, N);
    spmm_kernel<true><<<blocks, threads, 0, stream>>>(adj_vals, cols, row_ptr,
                                                      (const float4*)y4, bias, x4, N);
    // layer 3
    spmm_kernel<false><<<blocks, threads, 0, stream>>>(w_vals, cols, row_ptr,
                                                       (const float4*)x4, nullptr, y4, N);
    spmm_kernel<true><<<blocks, threads, 0, stream>>>(adj_vals, cols, row_ptr,
                                                      (const float4*)y4, bias, x4, N);
}

// Round 2
// 266.456 us; speedup vs baseline: 1.1285x; 1.1285x over previous
//
#include <hip/hip_runtime.h>

// AdultConnectomeNetwork: 3 layers of  x = A @ (W @ x) + bias
// A and W share the same sorted-COO pattern (rows sorted, cols random).
// N=50000, NNZ=800000, B=64, L=3.
//
// R1: the SpMM inner loop was a serial dependent chain (cols[e] -> gather).
// Batch edges in chunks of 8: load 8 (col,val) pairs, then 8 independent
// 256B gathers in flight, then FMAs. Tail edges are masked inside the same
// batched loop (v=0 -> harmless gather of x[0]) to keep ILP on remainders.

#define EDGE_BATCH 8

__global__ void build_row_ptr_kernel(const int* __restrict__ rows, int nnz,
                                     int n, int* __restrict__ row_ptr) {
    int r = blockIdx.x * blockDim.x + threadIdx.x;
    if (r > n) return;
    int lo = 0, hi = nnz;
    while (lo < hi) {
        int mid = (lo + hi) >> 1;
        if (rows[mid] < r) lo = mid + 1; else hi = mid;
    }
    row_ptr[r] = lo;
}

// y[r, :] = sum_{e in row r} vals[e] * x[cols[e], :]  (+ bias[r] if ADD_BIAS)
// 16 threads per row; lane l owns columns [4l, 4l+4).
template <bool ADD_BIAS>
__global__ void spmm_kernel(const float* __restrict__ vals,
                            const int* __restrict__ cols,
                            const int* __restrict__ row_ptr,
                            const float4* __restrict__ xin,  // [n*16] float4
                            const float* __restrict__ bias,
                            float4* __restrict__ yout,       // [n*16] float4
                            int n) {
    const int groups_per_block = blockDim.x >> 4;           // 16 lanes/row
    const int row = blockIdx.x * groups_per_block + (threadIdx.x >> 4);
    const int lane = threadIdx.x & 15;
    if (row >= n) return;

    const int e0 = row_ptr[row];
    const int e1 = row_ptr[row + 1];

    float4 acc = make_float4(0.f, 0.f, 0.f, 0.f);

    for (int e = e0; e < e1; e += EDGE_BATCH) {
        int   c[EDGE_BATCH];
        float v[EDGE_BATCH];
        // Phase 1: batched (col, val) loads — independent, masked tail.
#pragma unroll
        for (int j = 0; j < EDGE_BATCH; ++j) {
            const int idx = e + j;
            const bool ok = idx < e1;
            c[j] = ok ? cols[idx] : 0;
            v[j] = ok ? vals[idx] : 0.f;
        }
        // Phase 2: 8 independent 256B row gathers in flight.
        float4 xv[EDGE_BATCH];
#pragma unroll
        for (int j = 0; j < EDGE_BATCH; ++j) {
            xv[j] = xin[c[j] * 16 + lane];
        }
        // Phase 3: FMAs.
#pragma unroll
        for (int j = 0; j < EDGE_BATCH; ++j) {
            acc.x += v[j] * xv[j].x;
            acc.y += v[j] * xv[j].y;
            acc.z += v[j] * xv[j].z;
            acc.w += v[j] * xv[j].w;
        }
    }

    if (ADD_BIAS) {
        const float b = bias[row];
        acc.x += b; acc.y += b; acc.z += b; acc.w += b;
    }
    yout[row * 16 + lane] = acc;
}

extern "C" void kernel_launch(void* const* d_in, const int* in_sizes, int n_in,
                              void* d_out, int out_size, void* d_ws, size_t ws_size,
                              hipStream_t stream) {
    const float* x_in     = (const float*)d_in[0];  // (N, 64)
    const float* adj_vals = (const float*)d_in[1];  // (NNZ,)
    const float* w_vals   = (const float*)d_in[2];  // (NNZ,)
    const float* bias     = (const float*)d_in[3];  // (N,)
    const int*   rows     = (const int*)d_in[4];    // (NNZ,) sorted
    const int*   cols     = (const int*)d_in[5];    // (NNZ,)
    // d_in[6] = n_layers (device scalar); structurally 3 in this problem.

    const int N   = in_sizes[3];
    const int NNZ = in_sizes[1];

    // Workspace layout: row_ptr (N+1 ints, 256B-aligned), then y buffer (N*64 f32)
    int* row_ptr = (int*)d_ws;
    size_t rp_bytes = ((size_t)(N + 1) * sizeof(int) + 255) & ~(size_t)255;
    float* ybuf = (float*)((char*)d_ws + rp_bytes);

    float* xbuf = (float*)d_out;   // ping-pong x lives in d_out

    // 1) CSR row pointers
    {
        int threads = 256;
        int blocks = (N + 1 + threads - 1) / threads;
        build_row_ptr_kernel<<<blocks, threads, 0, stream>>>(rows, NNZ, N, row_ptr);
    }

    // 2) Three layers: y = W@x ; x = A@y + bias
    const int threads = 256;
    const int rows_per_block = threads / 16;
    const int blocks = (N + rows_per_block - 1) / rows_per_block;

    const float4* x4_in = (const float4*)x_in;
    float4* y4 = (float4*)ybuf;
    float4* x4 = (float4*)xbuf;

    // layer 1
    spmm_kernel<false><<<blocks, threads, 0, stream>>>(w_vals, cols, row_ptr,
                                                       x4_in, nullptr, y4, N);
    spmm_kernel<true><<<blocks, threads, 0, stream>>>(adj_vals, cols, row_ptr,
                                                      (const float4*)y4, bias, x4, N);
    // layer 2
    spmm_kernel<false><<<blocks, threads, 0, stream>>>(w_vals, cols, row_ptr,
                                                       (const float4*)x4, nullptr, y4, N);
    spmm_kernel<true><<<blocks, threads, 0, stream>>>(adj_vals, cols, row_ptr,
                                                      (const float4*)y4, bias, x4, N);
    // layer 3
    spmm_kernel<false><<<blocks, threads, 0, stream>>>(w_vals, cols, row_ptr,
                                                       (const float4*)x4, nullptr, y4, N);
    spmm_kernel<true><<<blocks, threads, 0, stream>>>(adj_vals, cols, row_ptr,
                                                      (const float4*)y4, bias, x4, N);
}

// Round 3
// 222.864 us; speedup vs baseline: 1.3492x; 1.1956x over previous
//
#include <hip/hip_runtime.h>
#include <hip/hip_fp16.h>

// AdultConnectomeNetwork: 3 layers of  x = A @ (W @ x) + bias
// A and W share the same sorted-COO pattern (rows sorted, cols random).
// N=50000, NNZ=800000, B=64, L=3.
//
// R2: gather traffic (205 MB of random 256B rows per SpMM, ~4.7 TB/s) is the
// floor -> store intermediates as fp16 so each gathered row is 128B (one L2
// line). fp32 accumulate, fp16 round only on store. Input pre-converted to
// fp16 once; final SpMM writes fp32 directly to d_out.

#define EDGE_BATCH 8

__global__ void build_row_ptr_kernel(const int* __restrict__ rows, int nnz,
                                     int n, int* __restrict__ row_ptr) {
    int r = blockIdx.x * blockDim.x + threadIdx.x;
    if (r > n) return;
    int lo = 0, hi = nnz;
    while (lo < hi) {
        int mid = (lo + hi) >> 1;
        if (rows[mid] < r) lo = mid + 1; else hi = mid;
    }
    row_ptr[r] = lo;
}

// fp32 (N*64) -> fp16 (N*64); one thread per 4 elements.
__global__ void f32_to_f16_kernel(const float4* __restrict__ in,
                                  uint2* __restrict__ out, int n4) {
    int i = blockIdx.x * blockDim.x + threadIdx.x;
    if (i >= n4) return;
    float4 v = in[i];
    __half2 h0 = __floats2half2_rn(v.x, v.y);
    __half2 h1 = __floats2half2_rn(v.z, v.w);
    uint2 r;
    r.x = *(unsigned int*)&h0;
    r.y = *(unsigned int*)&h1;
    out[i] = r;
}

// y[r,:] = sum_e vals[e] * x16[cols[e],:]  (+bias[r]); x16 is fp16.
// 16 lanes per row, lane l owns columns [4l, 4l+4) as one uint2 (4 halves).
template <bool ADD_BIAS, bool OUT_F32>
__global__ void spmm_f16_kernel(const float* __restrict__ vals,
                                const int* __restrict__ cols,
                                const int* __restrict__ row_ptr,
                                const uint2* __restrict__ xin,   // [n*16] fp16x4
                                const float* __restrict__ bias,
                                uint2* __restrict__ yout16,      // [n*16] fp16x4
                                float4* __restrict__ yout32,     // [n*16] fp32x4
                                int n) {
    const int groups_per_block = blockDim.x >> 4;
    const int row = blockIdx.x * groups_per_block + (threadIdx.x >> 4);
    const int lane = threadIdx.x & 15;
    if (row >= n) return;

    const int e0 = row_ptr[row];
    const int e1 = row_ptr[row + 1];

    float4 acc = make_float4(0.f, 0.f, 0.f, 0.f);

    for (int e = e0; e < e1; e += EDGE_BATCH) {
        int   c[EDGE_BATCH];
        float v[EDGE_BATCH];
#pragma unroll
        for (int j = 0; j < EDGE_BATCH; ++j) {
            const int idx = e + j;
            const bool ok = idx < e1;
            c[j] = ok ? cols[idx] : 0;
            v[j] = ok ? vals[idx] : 0.f;
        }
        uint2 raw[EDGE_BATCH];
#pragma unroll
        for (int j = 0; j < EDGE_BATCH; ++j) {
            raw[j] = xin[c[j] * 16 + lane];   // 8B/lane, 128B/row, coalesced
        }
#pragma unroll
        for (int j = 0; j < EDGE_BATCH; ++j) {
            const __half2 h0 = *(const __half2*)&raw[j].x;
            const __half2 h1 = *(const __half2*)&raw[j].y;
            const float2 f0 = __half22float2(h0);
            const float2 f1 = __half22float2(h1);
            acc.x += v[j] * f0.x;
            acc.y += v[j] * f0.y;
            acc.z += v[j] * f1.x;
            acc.w += v[j] * f1.y;
        }
    }

    if (ADD_BIAS) {
        const float b = bias[row];
        acc.x += b; acc.y += b; acc.z += b; acc.w += b;
    }

    if (OUT_F32) {
        yout32[row * 16 + lane] = acc;
    } else {
        __half2 h0 = __floats2half2_rn(acc.x, acc.y);
        __half2 h1 = __floats2half2_rn(acc.z, acc.w);
        uint2 r;
        r.x = *(unsigned int*)&h0;
        r.y = *(unsigned int*)&h1;
        yout16[row * 16 + lane] = r;
    }
}

extern "C" void kernel_launch(void* const* d_in, const int* in_sizes, int n_in,
                              void* d_out, int out_size, void* d_ws, size_t ws_size,
                              hipStream_t stream) {
    const float* x_in     = (const float*)d_in[0];  // (N, 64)
    const float* adj_vals = (const float*)d_in[1];  // (NNZ,)
    const float* w_vals   = (const float*)d_in[2];  // (NNZ,)
    const float* bias     = (const float*)d_in[3];  // (N,)
    const int*   rows     = (const int*)d_in[4];    // (NNZ,) sorted
    const int*   cols     = (const int*)d_in[5];    // (NNZ,)
    // d_in[6] = n_layers (device scalar); structurally 3.

    const int N   = in_sizes[3];
    const int NNZ = in_sizes[1];

    // Workspace: row_ptr | xh (N*64 fp16) | yh (N*64 fp16)
    int* row_ptr = (int*)d_ws;
    size_t rp_bytes = ((size_t)(N + 1) * sizeof(int) + 255) & ~(size_t)255;
    uint2* xh = (uint2*)((char*)d_ws + rp_bytes);                       // N*16 uint2
    uint2* yh = (uint2*)((char*)d_ws + rp_bytes + (size_t)N * 16 * 8);  // N*16 uint2

    // 1) CSR row pointers
    {
        int threads = 256;
        int blocks = (N + 1 + threads - 1) / threads;
        build_row_ptr_kernel<<<blocks, threads, 0, stream>>>(rows, NNZ, N, row_ptr);
    }
    // 2) input fp32 -> fp16
    {
        int n4 = N * 16;
        int threads = 256;
        int blocks = (n4 + threads - 1) / threads;
        f32_to_f16_kernel<<<blocks, threads, 0, stream>>>((const float4*)x_in, xh, n4);
    }

    const int threads = 256;
    const int rows_per_block = threads / 16;
    const int blocks = (N + rows_per_block - 1) / rows_per_block;
    float4* out32 = (float4*)d_out;

    // layer 1: yh = W@xh ; xh = A@yh + b
    spmm_f16_kernel<false, false><<<blocks, threads, 0, stream>>>(w_vals, cols, row_ptr,
                                                                  xh, nullptr, yh, nullptr, N);
    spmm_f16_kernel<true, false><<<blocks, threads, 0, stream>>>(adj_vals, cols, row_ptr,
                                                                 yh, bias, xh, nullptr, N);
    // layer 2
    spmm_f16_kernel<false, false><<<blocks, threads, 0, stream>>>(w_vals, cols, row_ptr,
                                                                  xh, nullptr, yh, nullptr, N);
    spmm_f16_kernel<true, false><<<blocks, threads, 0, stream>>>(adj_vals, cols, row_ptr,
                                                                 yh, bias, xh, nullptr, N);
    // layer 3: last SpMM writes fp32 to d_out
    spmm_f16_kernel<false, false><<<blocks, threads, 0, stream>>>(w_vals, cols, row_ptr,
                                                                  xh, nullptr, yh, nullptr, N);
    spmm_f16_kernel<true, true><<<blocks, threads, 0, stream>>>(adj_vals, cols, row_ptr,
                                                                yh, bias, nullptr, out32, N);
}